// Round 1
// baseline (1043.838 us; speedup 1.0000x reference)
//
#include <hip/hip_runtime.h>

// LocalWindowAttention: B=4, C=256, H=W=256, WS=8, heads=8, hd=32.
// Fully fused: one 512-thread block per 8x8 window (4096 blocks).
// LDS plan (132KB dynamic):
//   [0,32768)        xw   : [64 pos][256 ch] bf16, chunk-XOR swizzled; reused for attn-out
//   [32768,69632)    vbuf : [256 ch][72] bf16 (row 144B, 16B aligned, bank-spread pad)
//   [69632,102400)   qT   : [64][256] swizzled   (also x_tmp [256][66] in phase1/2, also P waves 0-3)
//   [102400,135168)  kT   : [64][256] swizzled   (also P waves 4-7)

typedef short short4v __attribute__((ext_vector_type(4)));
typedef short short8v __attribute__((ext_vector_type(8)));
typedef float f32x4  __attribute__((ext_vector_type(4)));

__device__ __forceinline__ short f2bf(float f) {
  unsigned u = __builtin_bit_cast(unsigned, f);
  u = u + 0x7fffu + ((u >> 16) & 1u);   // RNE to bf16
  return (short)(u >> 16);
}

// byte offset into a [64][256]-bf16 row-major tile (row r = position, col c = channel),
// 16B chunks XOR-swizzled by (r&7) so row-strided ds_read_b128 hit all bank groups.
__device__ __forceinline__ int swz_off(int r, int c) {
  return r * 512 + ((((c >> 3) ^ (r & 7)) << 4)) + ((c & 7) << 1);
}
// same idea for the per-wave P tile [64][64] bf16 (row 128B)
__device__ __forceinline__ int swz_p(int i, int j) {
  return i * 128 + ((((j >> 3) ^ (i & 7)) << 4)) + ((j & 7) << 1);
}

__global__ void conv_weights(const float* __restrict__ w0, const float* __restrict__ w1,
                             const float* __restrict__ w2, const float* __restrict__ w3,
                             short* __restrict__ o) {
  const float* src = blockIdx.y == 0 ? w0 : blockIdx.y == 1 ? w1 : blockIdx.y == 2 ? w2 : w3;
  int i = blockIdx.x * 256 + threadIdx.x;      // 0..16383 (float4 index)
  float4 v = ((const float4*)src)[i];
  short4v r;
  r[0] = f2bf(v.x); r[1] = f2bf(v.y); r[2] = f2bf(v.z); r[3] = f2bf(v.w);
  ((short4v*)(o + blockIdx.y * 65536))[i] = r;
}

__global__ __launch_bounds__(512, 2)
void fused_win_attn(const float* __restrict__ x,
                    const short* __restrict__ Wb,   // [4][256][256] bf16: Wq,Wk,Wv,Wo
                    float* __restrict__ out)
{
  extern __shared__ char smem[];
  char*  vbuf = smem + 32768;
  char*  qT   = smem + 69632;
  char*  kT   = smem + 102400;
  short* xtmp = (short*)(smem + 69632);   // [256][66] bf16 bounce (dead before qT/kT written)
  char*  Pb   = smem + 69632;             // per-wave 8KB P tiles (qT/kT region, dead by then)

  const int bid = blockIdx.x;
  const int win = (bid & 7) * 512 + (bid >> 3);   // XCD-bijective swizzle (4096 % 8 == 0)
  const int b   = win >> 10;
  const int wi  = win & 1023;
  const int h0  = (wi >> 5) << 3;
  const int w0  = (wi & 31) << 3;

  const int tid  = threadIdx.x;
  const int lane = tid & 63;
  const int wid  = tid >> 6;
  const int l15  = lane & 15;
  const int l4   = lane >> 4;

  const float* xbase = x + (size_t)b * (256 * 65536) + (size_t)h0 * 256 + w0;

  // ---- Phase 1: global fp32 -> x_tmp[c][p] bf16 (coalesced reads, contiguous LDS writes)
  #pragma unroll
  for (int i = 0; i < 32; ++i) {
    int f = tid + i * 512;            // 0..16383
    int c = f >> 6, p = f & 63;
    float vx = xbase[(size_t)c * 65536 + (p >> 3) * 256 + (p & 7)];
    xtmp[c * 66 + p] = f2bf(vx);
  }
  __syncthreads();

  // ---- Phase 2: transpose x_tmp -> xw[pos][chan] (66-pad rows: conflict-free column reads)
  #pragma unroll
  for (int i = 0; i < 32; ++i) {
    int f = tid + i * 512;
    int cc = f & 255, r = f >> 8;     // r uniform per wave-instr, cc lane-consecutive
    short vv = xtmp[cc * 66 + r];
    *(short*)(smem + swz_off(r, cc)) = vv;
  }
  __syncthreads();

  // ---- Phase 3: QKV projection GEMM. Stacked M-tiles st=0..47 (q:0-15,k:16-31,v:32-47),
  //      wave owns st = wid*6 .. wid*6+5. B-frag (xw) reused across the 6 M-tiles.
  {
    f32x4 acc[6][4] = {};
    #pragma unroll
    for (int kc = 0; kc < 8; ++kc) {
      const int ccol = kc * 32 + (l4 << 3);
      short8v af[6];
      #pragma unroll
      for (int t = 0; t < 6; ++t) {
        int st = wid * 6 + t;
        const short* W = Wb + (st >> 4) * 65536;
        int o0 = (st & 15) << 4;
        af[t] = *(const short8v*)(W + (o0 + l15) * 256 + ccol);
      }
      #pragma unroll
      for (int nt = 0; nt < 4; ++nt) {
        short8v bf = *(const short8v*)(smem + swz_off(nt * 16 + l15, ccol));
        #pragma unroll
        for (int t = 0; t < 6; ++t)
          acc[t][nt] = __builtin_amdgcn_mfma_f32_16x16x32_bf16(af[t], bf, acc[t][nt], 0, 0, 0);
      }
    }
    // D: acc[t][nt][jj] = D[o0 + 4*l4 + jj][nt*16 + l15]
    #pragma unroll
    for (int t = 0; t < 6; ++t) {
      int st = wid * 6 + t;
      int proj = st >> 4;
      int oc = ((st & 15) << 4) + (l4 << 2);
      #pragma unroll
      for (int nt = 0; nt < 4; ++nt) {
        int r = nt * 16 + l15;
        if (proj < 2) {               // q,k -> transposed swizzled tiles
          char* dst = (proj == 0) ? qT : kT;
          short4v pk;
          pk[0] = f2bf(acc[t][nt][0]); pk[1] = f2bf(acc[t][nt][1]);
          pk[2] = f2bf(acc[t][nt][2]); pk[3] = f2bf(acc[t][nt][3]);
          *(short4v*)(dst + swz_off(r, oc)) = pk;
        } else {                      // v -> natural [chan][pos], 144B rows
          #pragma unroll
          for (int jj = 0; jj < 4; ++jj)
            *((short*)(vbuf + (oc + jj) * 144) + r) = f2bf(acc[t][nt][jj]);
        }
      }
    }
  }
  __syncthreads();

  // ---- Phase 4: S = q^T k per head (head = wid), K=32 -> one MFMA K-step. Softmax in regs.
  const int h = wid;
  f32x4 s[4][4];
  {
    const int ccol = h * 32 + (l4 << 3);
    short8v qf[4], kf[4];
    #pragma unroll
    for (int mt = 0; mt < 4; ++mt)
      qf[mt] = *(const short8v*)(qT + swz_off(mt * 16 + l15, ccol));
    #pragma unroll
    for (int nt = 0; nt < 4; ++nt)
      kf[nt] = *(const short8v*)(kT + swz_off(nt * 16 + l15, ccol));
    #pragma unroll
    for (int mt = 0; mt < 4; ++mt)
      #pragma unroll
      for (int nt = 0; nt < 4; ++nt) {
        f32x4 z = {0.f, 0.f, 0.f, 0.f};
        s[mt][nt] = __builtin_amdgcn_mfma_f32_16x16x32_bf16(qf[mt], kf[nt], z, 0, 0, 0);
      }
  }
  {
    const float kscale = 0.17677669529663687f;   // hd^-0.5
    #pragma unroll
    for (int mt = 0; mt < 4; ++mt) {
      #pragma unroll
      for (int jj = 0; jj < 4; ++jj) {
        // row i = mt*16 + 4*l4 + jj lives across lanes (l15) x 4 N-tiles
        float m = fmaxf(fmaxf(s[mt][0][jj], s[mt][1][jj]), fmaxf(s[mt][2][jj], s[mt][3][jj]));
        m = fmaxf(m, __shfl_xor(m, 1));
        m = fmaxf(m, __shfl_xor(m, 2));
        m = fmaxf(m, __shfl_xor(m, 4));
        m = fmaxf(m, __shfl_xor(m, 8));
        float sum = 0.f;
        #pragma unroll
        for (int nt = 0; nt < 4; ++nt) {
          float e = __expf((s[mt][nt][jj] - m) * kscale);
          s[mt][nt][jj] = e;
          sum += e;
        }
        sum += __shfl_xor(sum, 1);
        sum += __shfl_xor(sum, 2);
        sum += __shfl_xor(sum, 4);
        sum += __shfl_xor(sum, 8);
        float inv = 1.0f / sum;
        #pragma unroll
        for (int nt = 0; nt < 4; ++nt) s[mt][nt][jj] *= inv;
      }
    }
  }
  __syncthreads();   // all qT/kT reads done -> safe to overwrite with P

  // ---- Phase 5: P -> LDS (own-wave tile, swizzled), then PV
  char* P = Pb + wid * 8192;
  #pragma unroll
  for (int mt = 0; mt < 4; ++mt) {
    int ib = mt * 16 + (l4 << 2);
    #pragma unroll
    for (int nt = 0; nt < 4; ++nt) {
      int j = nt * 16 + l15;
      #pragma unroll
      for (int jj = 0; jj < 4; ++jj)
        *(short*)(P + swz_p(ib + jj, j)) = f2bf(s[mt][nt][jj]);
    }
  }
  f32x4 oacc[4][2] = {};
  #pragma unroll
  for (int kj = 0; kj < 2; ++kj) {
    const int jcol = kj * 32 + (l4 << 3);
    short8v vf[2];
    #pragma unroll
    for (int nc = 0; nc < 2; ++nc) {
      int cc = h * 32 + nc * 16 + l15;
      vf[nc] = *(const short8v*)(vbuf + cc * 144 + jcol * 2);
    }
    #pragma unroll
    for (int mt = 0; mt < 4; ++mt) {
      short8v pf = *(const short8v*)(P + swz_p(mt * 16 + l15, jcol));
      #pragma unroll
      for (int nc = 0; nc < 2; ++nc)
        oacc[mt][nc] = __builtin_amdgcn_mfma_f32_16x16x32_bf16(pf, vf[nc], oacc[mt][nc], 0, 0, 0);
    }
  }
  // attn-out (transposed, swizzled) into the xw region (dead since phase 3)
  #pragma unroll
  for (int mt = 0; mt < 4; ++mt) {
    int ib = mt * 16 + (l4 << 2);
    #pragma unroll
    for (int nc = 0; nc < 2; ++nc) {
      int cc = h * 32 + nc * 16 + l15;
      #pragma unroll
      for (int jj = 0; jj < 4; ++jj)
        *(short*)(smem + swz_off(ib + jj, cc)) = f2bf(oacc[mt][nc][jj]);
    }
  }
  __syncthreads();

  // ---- Phase 7: output projection Wo, wave owns M-tiles 2*wid, 2*wid+1
  const short* Wo = Wb + 3 * 65536;
  #pragma unroll
  for (int t = 0; t < 2; ++t) {
    int o0 = (wid * 2 + t) << 4;
    f32x4 acc2[4] = {};
    #pragma unroll
    for (int kc = 0; kc < 8; ++kc) {
      int ccol = kc * 32 + (l4 << 3);
      short8v af = *(const short8v*)(Wo + (o0 + l15) * 256 + ccol);
      #pragma unroll
      for (int nt = 0; nt < 4; ++nt) {
        short8v bf = *(const short8v*)(smem + swz_off(nt * 16 + l15, ccol));
        acc2[nt] = __builtin_amdgcn_mfma_f32_16x16x32_bf16(af, bf, acc2[nt], 0, 0, 0);
      }
    }
    int oc = o0 + (l4 << 2);
    #pragma unroll
    for (int nt = 0; nt < 4; ++nt) {
      int r = nt * 16 + l15;
      size_t base = (size_t)(b * 256 + oc) * 65536 + (size_t)(h0 + (r >> 3)) * 256 + (w0 + (r & 7));
      #pragma unroll
      for (int jj = 0; jj < 4; ++jj)
        out[base + (size_t)jj * 65536] = acc2[nt][jj];
    }
  }
}

extern "C" void kernel_launch(void* const* d_in, const int* in_sizes, int n_in,
                              void* d_out, int out_size, void* d_ws, size_t ws_size,
                              hipStream_t stream) {
  const float* x  = (const float*)d_in[0];
  const float* Wq = (const float*)d_in[1];
  const float* Wk = (const float*)d_in[2];
  const float* Wv = (const float*)d_in[3];
  const float* Wo = (const float*)d_in[4];
  float* out = (float*)d_out;
  short* wbf = (short*)d_ws;   // needs 4*65536*2 = 512KB of workspace

  // weights -> bf16 once per call (d_ws is re-poisoned before every timed launch)
  conv_weights<<<dim3(64, 4), 256, 0, stream>>>(Wq, Wk, Wv, Wo, wbf);

  (void)hipFuncSetAttribute((const void*)fused_win_attn,
                            hipFuncAttributeMaxDynamicSharedMemorySize, 135168);
  fused_win_attn<<<4096, 512, 135168, stream>>>(x, wbf, out);
}